// Round 1
// 613.422 us; speedup vs baseline: 1.2095x; 1.2095x over previous
//
#include <hip/hip_runtime.h>
#include <stdint.h>

#define NN 64
#define LDP 72            // padded row stride (bf16 elems) = 144 B: optimal bank spread
#define PL  (NN * LDP)    // plane size in shorts (4608)
#define DEG 30            // Chebyshev degree for log on [aLo, aHi]

typedef __attribute__((ext_vector_type(8))) short short8;   // 8 bf16 = 4 VGPRs
typedef __attribute__((ext_vector_type(4))) float f32x4;

#define MFMA(a, b, c) __builtin_amdgcn_mfma_f32_16x16x32_bf16((a), (b), (c), 0, 0, 0)

__device__ __forceinline__ float bf2f(uint32_t h) {
    union { uint32_t i; float f; } v; v.i = h << 16; return v.f;
}
__device__ __forceinline__ float ubf(uint32_t u) {
    union { uint32_t i; float f; } v; v.i = u; return v.f;
}
// packed RNE f32->bf16 x2: dst[15:0]=bf16(lo), dst[31:16]=bf16(hi)
__device__ __forceinline__ uint32_t cvtpk_bf16(float lo, float hi) {
    uint32_t r;
    asm("v_cvt_pk_bf16_f32 %0, %1, %2" : "=v"(r) : "v"(lo), "v"(hi));
    return r;
}
// split 4 f32 into packed hi/lo bf16 pairs (RNE hi, exact residual -> RNE lo)
__device__ __forceinline__ void split4(float v0, float v1, float v2, float v3,
                                       uint2& ph, uint2& pl) {
    uint32_t h01 = cvtpk_bf16(v0, v1);
    uint32_t h23 = cvtpk_bf16(v2, v3);
    float r0 = v0 - ubf(h01 << 16);
    float r1 = v1 - ubf(h01 & 0xFFFF0000u);
    float r2 = v2 - ubf(h23 << 16);
    float r3 = v3 - ubf(h23 & 0xFFFF0000u);
    ph.x = h01; ph.y = h23;
    pl.x = cvtpk_bf16(r0, r1);
    pl.y = cvtpk_bf16(r2, r3);
}
// Write 4 values (rows rbase..rbase+3, col c) TRANSPOSED: plane[c][rbase..+3].
// Legal because every matrix here is symmetric.
__device__ __forceinline__ void store_tile(short* Ph, short* Pl, int c, int rbase, f32x4 v) {
    uint2 ph, pl; split4(v[0], v[1], v[2], v[3], ph, pl);
    *(uint2*)(Ph + c * LDP + rbase) = ph;
    *(uint2*)(Pl + c * LDP + rbase) = pl;
}
__device__ __forceinline__ void store_tile_f(short* Ph, short* Pl, int c, int rbase,
                                             const float* v) {
    uint2 ph, pl; split4(v[0], v[1], v[2], v[3], ph, pl);
    *(uint2*)(Ph + c * LDP + rbase) = ph;
    *(uint2*)(Pl + c * LDP + rbase) = pl;
}

// acc[t] += A*B rows [16wv,16wv+16) x cols [16t,16t+16), split-precision (3 MFMA/term).
__device__ __forceinline__ void mm_mfma(const short* Ah, const short* Al,
                                        const short* Bh, const short* Bl,
                                        int wv, int fr, int fq, f32x4* acc) {
#pragma unroll
    for (int kc = 0; kc < 2; ++kc) {
        const int ao = (16 * wv + fr) * LDP + kc * 32 + fq * 8;
        const short8 ah = *(const short8*)(Ah + ao);
        const short8 al = *(const short8*)(Al + ao);
        const int bo = fr * LDP + kc * 32 + fq * 8;
#pragma unroll
        for (int t = 0; t < 4; ++t) {
            const short8 bh = *(const short8*)(Bh + bo + t * (16 * LDP));
            const short8 bl = *(const short8*)(Bl + bo + t * (16 * LDP));
            acc[t] = MFMA(ah, bh, acc[t]);
            acc[t] = MFMA(ah, bl, acc[t]);
            acc[t] = MFMA(al, bh, acc[t]);
        }
    }
}

// One Clenshaw step with C-in folding: P := (ck*I - P) + (2T)*B, store P hi/lo to W.
// P is both the b_{k+2} input and the b_k output (ping-pong handled by caller).
__device__ __forceinline__ void clen_step(f32x4* P,
                                          const short8* a2h, const short8* a2l,
                                          const short* Bh, const short* Bl,
                                          short* Wh, short* Wl,
                                          float ck, const float* dm,
                                          int fr, int fq, int rbase) {
#pragma unroll
    for (int t = 0; t < 4; ++t)
#pragma unroll
        for (int r = 0; r < 4; ++r)
            P[t][r] = fmaf(ck, dm[t * 4 + r], -P[t][r]);
#pragma unroll
    for (int kc = 0; kc < 2; ++kc) {
        const int bo = fr * LDP + kc * 32 + fq * 8;
#pragma unroll
        for (int t = 0; t < 4; ++t) {
            const short8 bh = *(const short8*)(Bh + bo + t * (16 * LDP));
            const short8 bl = *(const short8*)(Bl + bo + t * (16 * LDP));
            P[t] = MFMA(a2h[kc], bh, P[t]);
            P[t] = MFMA(a2h[kc], bl, P[t]);
            P[t] = MFMA(a2l[kc], bh, P[t]);
        }
    }
#pragma unroll
    for (int t = 0; t < 4; ++t)
        store_tile(Wh, Wl, 16 * t + fr, rbase, P[t]);
    __syncthreads();
}

__global__ __launch_bounds__(256, 4)
void spdlogexp(const float* __restrict__ fin,
               const float* __restrict__ win,
               float* __restrict__ outp) {
    __shared__ __align__(16) short lds[4 * PL];   // 36864 B
    __shared__ float wsh[NN];
    __shared__ float cheb[DEG + 1];

    const int tid = threadIdx.x;
    const int blk = blockIdx.x;
    const int lane = tid & 63;
    const int wv = tid >> 6;          // wave id: owns C rows [16wv, 16wv+16)
    const int fr = lane & 15;         // A row / B col / C col (within 16)
    const int fq = lane >> 4;         // quad
    const int rbase = 16 * wv + 4 * fq;  // C-frag absolute row base (+reg 0..3)

    short* P0h = lds;
    short* P0l = lds + PL;
    short* P1h = lds + 2 * PL;
    short* P1l = lds + 3 * PL;

    const float aLo = 0.09f, aHi = 6.3f;
    const float mC = 0.5f * (aLo + aHi), rC = 0.5f * (aHi - aLo);
    const float invR2 = 2.0f / rC;    // store 2T so the Clenshaw 2x folds into the A operand

    // ---- Phase 0: load X (f32, coalesced), 2T = 2(X - mC I)/rC -> hi/lo bf16 in P0 ----
    {
        const float4* src = (const float4*)(fin + (size_t)blk * (NN * NN));
#pragma unroll
        for (int c = 0; c < 4; ++c) {
            int v4 = c * 256 + tid;
            float4 v = src[v4];
            int e0 = v4 << 2;
            int i = e0 >> 6, j = e0 & 63;     // row i, cols j..j+3
            float t0 = (v.x - ((j + 0 == i) ? mC : 0.0f)) * invR2;
            float t1 = (v.y - ((j + 1 == i) ? mC : 0.0f)) * invR2;
            float t2 = (v.z - ((j + 2 == i) ? mC : 0.0f)) * invR2;
            float t3 = (v.w - ((j + 3 == i) ? mC : 0.0f)) * invR2;
            uint2 ph, pl; split4(t0, t1, t2, t3, ph, pl);
            *(uint2*)(P0h + i * LDP + j) = ph;   // row-major here: plane[i][j..j+3]
            *(uint2*)(P0l + i * LDP + j) = pl;
        }
    }
    if (tid < NN) wsh[tid] = win[(size_t)blk * NN + tid];
    if (tid <= DEG) {
        // log(mC + rC t) = log(Cc) - 2 sum_k (u^k/k) T_k(t);  u<0!
        float mr = mC / rC;
        float u = -(mr - sqrtf(mr * mr - 1.0f));
        float Cc = -rC / (2.0f * u);
        if (tid == 0) cheb[0] = logf(Cc);
        else {
            float pu = powf(-u, (float)tid);          // |u|^k
            if (tid & 1) pu = -pu;                    // restore sign
            cheb[tid] = -2.0f * pu / (float)tid;
        }
    }
    __syncthreads();

    // ---- Cache 2T A-fragments in registers (A operand of every Clenshaw matmul) ----
    short8 a2h[2], a2l[2];
#pragma unroll
    for (int kc = 0; kc < 2; ++kc) {
        int ao = (16 * wv + fr) * LDP + kc * 32 + fq * 8;
        a2h[kc] = *(const short8*)(P0h + ao);
        a2l[kc] = *(const short8*)(P0l + ao);
    }

    // ---- diag mask at C-frag positions (fixed per thread) ----
    float dm[16];
#pragma unroll
    for (int t = 0; t < 4; ++t)
#pragma unroll
        for (int r = 0; r < 4; ++r)
            dm[t * 4 + r] = (rbase + r == 16 * t + fr) ? 1.0f : 0.0f;

    // ---- Clenshaw init: accA = b_DEG = c_DEG I ; accB = b_{DEG-1} = 2 c_DEG T + c_{DEG-1} I ----
    f32x4 accA[4], accB[4];
    {
        const float cD = cheb[DEG], cD1 = cheb[DEG - 1];
#pragma unroll
        for (int t = 0; t < 4; ++t)
#pragma unroll
            for (int r = 0; r < 4; ++r) {
                int row = rbase + r, col = 16 * t + fr;
                float t2v = bf2f((uint16_t)P0h[row * LDP + col]);  // (2T) hi = 2*T_hi exactly
                accB[t][r] = fmaf(cD, t2v, cD1 * dm[t * 4 + r]);
                accA[t][r] = cD * dm[t * 4 + r];
            }
#pragma unroll
        for (int t = 0; t < 4; ++t)
            store_tile(P1h, P1l, 16 * t + fr, rbase, accB[t]);
    }
    __syncthreads();

    // ---- Clenshaw pairs: accA takes k = 28,26,..,2 ; accB takes k = 27,25,..,1.
    //      Each step: b_k = (c_k I - b_{k+2}) + (2T) b_{k+1}, b_{k+1} read from LDS. ----
    for (int k = DEG - 2; k > 0; k -= 2) {
        clen_step(accA, a2h, a2l, P1h, P1l, P0h, P0l, cheb[k],     dm, fr, fq, rbase);
        clen_step(accB, a2h, a2l, P0h, P0l, P1h, P1l, cheb[k - 1], dm, fr, fq, rbase);
    }
    // final k=0: accA := 2*(c0 I - b_2) + (2T)*b_1 = 2L   (b_1 in P1; 0.5 folds into weights)
    {
        const float c0 = cheb[0];
#pragma unroll
        for (int t = 0; t < 4; ++t)
#pragma unroll
            for (int r = 0; r < 4; ++r)
                accA[t][r] = 2.0f * fmaf(c0, dm[t * 4 + r], -accA[t][r]);
#pragma unroll
        for (int kc = 0; kc < 2; ++kc) {
            const int bo = fr * LDP + kc * 32 + fq * 8;
#pragma unroll
            for (int t = 0; t < 4; ++t) {
                const short8 bh = *(const short8*)(P1h + bo + t * (16 * LDP));
                const short8 bl = *(const short8*)(P1l + bo + t * (16 * LDP));
                accA[t] = MFMA(a2h[kc], bh, accA[t]);
                accA[t] = MFMA(a2h[kc], bl, accA[t]);
                accA[t] = MFMA(a2l[kc], bh, accA[t]);
            }
        }
    }

    // ---- A = (w_i w_j / 16) L = w_i w_j * 0.03125 * (2L)  (scaling-squaring s=4) ----
    float aF[16];
#pragma unroll
    for (int t = 0; t < 4; ++t) {
        float wc = wsh[16 * t + fr];
#pragma unroll
        for (int r = 0; r < 4; ++r)
            aF[t * 4 + r] = wsh[rbase + r] * wc * 0.03125f * accA[t][r];
    }
    short* Xh = P0h; short* Xl = P0l;   // P0 free: b_2 last read at the k=1 step (barriered)
    short* Yh = P1h; short* Yl = P1l;
#pragma unroll
    for (int t = 0; t < 4; ++t)
        store_tile_f(Xh, Xl, 16 * t + fr, rbase, &aF[t * 4]);
    __syncthreads();

    // ---- M2 = A*A -> Y ----
    float m2F[16];
    {
        f32x4 acc[4];
#pragma unroll
        for (int t = 0; t < 4; ++t) acc[t] = (f32x4){0.f, 0.f, 0.f, 0.f};
        mm_mfma(Xh, Xl, Xh, Xl, wv, fr, fq, acc);
#pragma unroll
        for (int t = 0; t < 4; ++t) {
#pragma unroll
            for (int r = 0; r < 4; ++r) m2F[t * 4 + r] = acc[t][r];
            store_tile(Yh, Yl, 16 * t + fr, rbase, acc[t]);
        }
    }
    __syncthreads();

    // ---- M3 = A*M2 (frags only), then G -> X, M3 -> Y ----
    float b0F[16];
    {
        f32x4 acc[4];
#pragma unroll
        for (int t = 0; t < 4; ++t) acc[t] = (f32x4){0.f, 0.f, 0.f, 0.f};
        mm_mfma(Xh, Xl, Yh, Yl, wv, fr, fq, acc);
        float gF[16];
#pragma unroll
        for (int t = 0; t < 4; ++t)
#pragma unroll
            for (int r = 0; r < 4; ++r) {
                float d = dm[t * 4 + r];
                float a = aF[t * 4 + r], m2 = m2F[t * 4 + r], m3 = acc[t][r];
                b0F[t * 4 + r] = d + a + 0.5f * m2;
                gF[t * 4 + r] = (1.0f / 6.0f) * d + (1.0f / 24.0f) * a +
                                (1.0f / 120.0f) * m2 + (1.0f / 720.0f) * m3;
            }
        __syncthreads();   // everyone done reading A(X), M2(Y)
#pragma unroll
        for (int t = 0; t < 4; ++t) {
            store_tile_f(Xh, Xl, 16 * t + fr, rbase, &gF[t * 4]);
            store_tile(Yh, Yl, 16 * t + fr, rbase, acc[t]);
        }
    }
    __syncthreads();

    // ---- P = b0 + G*M3 -> P0 (fixed home so squaring chain ends reading P1) ----
    {
        f32x4 acc[4];
#pragma unroll
        for (int t = 0; t < 4; ++t) acc[t] = (f32x4){0.f, 0.f, 0.f, 0.f};
        mm_mfma(Xh, Xl, Yh, Yl, wv, fr, fq, acc);
        float pF[16];
#pragma unroll
        for (int t = 0; t < 4; ++t)
#pragma unroll
            for (int r = 0; r < 4; ++r) pF[t * 4 + r] = acc[t][r] + b0F[t * 4 + r];
        __syncthreads();   // everyone done reading G/M3
#pragma unroll
        for (int t = 0; t < 4; ++t)
            store_tile_f(P0h, P0l, 16 * t + fr, rbase, &pF[t * 4]);
    }
    __syncthreads();

    // ---- 4 squarings: exp(M) = P^16. P0 -> P1 -> P0 -> P1 -> (stage) ----
    const short *Sh = P0h, *Sl = P0l;
    short *Dh = P1h, *Dl = P1l;
    for (int it = 0; it < 4; ++it) {
        f32x4 acc[4];
#pragma unroll
        for (int t = 0; t < 4; ++t) acc[t] = (f32x4){0.f, 0.f, 0.f, 0.f};
        mm_mfma(Sh, Sl, Sh, Sl, wv, fr, fq, acc);
        if (it < 3) {
#pragma unroll
            for (int t = 0; t < 4; ++t)
                store_tile(Dh, Dl, 16 * t + fr, rbase, acc[t]);
            __syncthreads();
            const short* th = Sh; const short* tl = Sl;
            Sh = Dh; Sl = Dl; Dh = (short*)th; Dl = (short*)tl;
        } else {
            // stage transposed f32 (stride 68 breaks bank conflicts) over P0 region;
            // final mm read from P1 -- no overlap.
            float* stg = (float*)lds;
#pragma unroll
            for (int t = 0; t < 4; ++t) {
                f32x4 v = acc[t];
                *(f32x4*)(stg + (16 * t + fr) * 68 + rbase) = v;
            }
        }
    }
    __syncthreads();

    // ---- coalesced float4 store ----
    {
        const float* stg = (const float*)lds;
        float4* dst = (float4*)(outp + (size_t)blk * (NN * NN));
#pragma unroll
        for (int c = 0; c < 4; ++c) {
            int v4 = c * 256 + tid;
            int e0 = v4 << 2, i = e0 >> 6, j = e0 & 63;
            float4 v = *(const float4*)(stg + i * 68 + j);
            dst[v4] = v;
        }
    }
}

extern "C" void kernel_launch(void* const* d_in, const int* in_sizes, int n_in,
                              void* d_out, int out_size, void* d_ws, size_t ws_size,
                              hipStream_t stream) {
    const float* f = (const float*)d_in[0];
    const float* w = (const float*)d_in[1];
    float* o = (float*)d_out;
    int B = in_sizes[0] / (NN * NN);
    spdlogexp<<<dim3(B), dim3(256), 0, stream>>>(f, w, o);
}

// Round 2
// 583.859 us; speedup vs baseline: 1.2707x; 1.0506x over previous
//
#include <hip/hip_runtime.h>
#include <stdint.h>

#define NN 64
#define PLN 4096          // plane size in shorts: 64 rows x 64 shorts, swizzled, NO padding
#define DEG 30            // Chebyshev degree for log on [aLo, aHi]

typedef __attribute__((ext_vector_type(8))) short short8;   // 8 bf16 = 4 VGPRs
typedef __attribute__((ext_vector_type(4))) float f32x4;
typedef __attribute__((ext_vector_type(16))) float f32x16;

#define MFMA32(a, b, c) __builtin_amdgcn_mfma_f32_32x32x16_bf16((a), (b), (c), 0, 0, 0)

__device__ __forceinline__ float bf2f(uint32_t h) {
    union { uint32_t i; float f; } v; v.i = h << 16; return v.f;
}
__device__ __forceinline__ float ubf(uint32_t u) {
    union { uint32_t i; float f; } v; v.i = u; return v.f;
}
// packed RNE f32->bf16 x2: dst[15:0]=bf16(lo), dst[31:16]=bf16(hi)
__device__ __forceinline__ uint32_t cvtpk_bf16(float lo, float hi) {
    uint32_t r;
    asm("v_cvt_pk_bf16_f32 %0, %1, %2" : "=v"(r) : "v"(lo), "v"(hi));
    return r;
}
// split 4 f32 into packed hi/lo bf16 pairs (RNE hi, exact residual -> RNE lo)
__device__ __forceinline__ void split4(float v0, float v1, float v2, float v3,
                                       uint2& ph, uint2& pl) {
    uint32_t h01 = cvtpk_bf16(v0, v1);
    uint32_t h23 = cvtpk_bf16(v2, v3);
    float r0 = v0 - ubf(h01 << 16);
    float r1 = v1 - ubf(h01 & 0xFFFF0000u);
    float r2 = v2 - ubf(h23 << 16);
    float r3 = v3 - ubf(h23 & 0xFFFF0000u);
    ph.x = h01; ph.y = h23;
    pl.x = cvtpk_bf16(r0, r1);
    pl.y = cvtpk_bf16(r2, r3);
}
// swizzled short-index of logical (r, c): 16B-block XOR swizzle breaks all bank conflicts
__device__ __forceinline__ int swz(int r, int c) {
    return r * 64 + ((((c >> 3) ^ (r & 7)) << 3) | (c & 7));
}

// store a 32x32 C-tile (16 regs) transposed into hi/lo planes at precomputed soff[4]
__device__ __forceinline__ void store16(short* Ph, short* Pl, const int* soff, const f32x16 v) {
#pragma unroll
    for (int g = 0; g < 4; ++g) {
        uint2 ph, pl; split4(v[4 * g], v[4 * g + 1], v[4 * g + 2], v[4 * g + 3], ph, pl);
        *(uint2*)(Ph + soff[g]) = ph;
        *(uint2*)(Pl + soff[g]) = pl;
    }
}
__device__ __forceinline__ void store16f(short* Ph, short* Pl, const int* soff, const float* v) {
#pragma unroll
    for (int g = 0; g < 4; ++g) {
        uint2 ph, pl; split4(v[4 * g], v[4 * g + 1], v[4 * g + 2], v[4 * g + 3], ph, pl);
        *(uint2*)(Ph + soff[g]) = ph;
        *(uint2*)(Pl + soff[g]) = pl;
    }
}

// acc += X*Y on this wave's 32x32 quadrant; both operands from LDS (split precision, 3 MFMA/k-step)
__device__ __forceinline__ void mm32(const short* Ah, const short* Al,
                                     const short* Bh, const short* Bl,
                                     const int* aoff, const int* boff, f32x16& acc) {
#pragma unroll
    for (int kk = 0; kk < 4; ++kk) {
        const short8 ah = *(const short8*)(Ah + aoff[kk]);
        const short8 al = *(const short8*)(Al + aoff[kk]);
        const short8 bh = *(const short8*)(Bh + boff[kk]);
        const short8 bl = *(const short8*)(Bl + boff[kk]);
        acc = MFMA32(ah, bh, acc);
        acc = MFMA32(ah, bl, acc);
        acc = MFMA32(al, bh, acc);
    }
}

// One Clenshaw step with C-in folding: P := (ck*I - P) + (2T)*B, store to W, barrier.
__device__ __forceinline__ void clen_step32(f32x16& P,
                                            const short8* a2h, const short8* a2l,
                                            const short* Bh, const short* Bl,
                                            short* Wh, short* Wl,
                                            float ck, const float* dm,
                                            const int* boff, const int* soff) {
#pragma unroll
    for (int i = 0; i < 16; ++i) P[i] = fmaf(ck, dm[i], -P[i]);
#pragma unroll
    for (int kk = 0; kk < 4; ++kk) {
        const short8 bh = *(const short8*)(Bh + boff[kk]);
        const short8 bl = *(const short8*)(Bl + boff[kk]);
        P = MFMA32(a2h[kk], bh, P);
        P = MFMA32(a2h[kk], bl, P);
        P = MFMA32(a2l[kk], bh, P);
    }
    store16(Wh, Wl, soff, P);
    __syncthreads();
}

__global__ __launch_bounds__(256, 4)
void spdlogexp(const float* __restrict__ fin,
               const float* __restrict__ win,
               float* __restrict__ outp) {
    __shared__ __align__(16) short lds[4 * PLN];   // 32768 B
    __shared__ __align__(16) float wsh[NN];
    __shared__ float cheb[DEG + 1];

    const int tid = threadIdx.x;
    const int blk = blockIdx.x;
    const int lane = tid & 63;
    const int wv = tid >> 6;
    const int wr = wv >> 1;           // row quadrant [32wr, 32wr+32)
    const int wc = wv & 1;            // col quadrant [32wc, 32wc+32)
    const int lh = lane >> 5;         // half (k-split within MFMA)
    const int l31 = lane & 31;
    const int l7 = lane & 7;

    short* P0h = lds;
    short* P0l = lds + PLN;
    short* P1h = lds + 2 * PLN;
    short* P1l = lds + 3 * PLN;

    // ---- per-thread swizzled LDS offsets ----
    // A-frag: row ar, k = kk*16 + 8*lh + e  -> logical 16B block (2kk+lh), XOR row&7
    // B-frag: col br (plane row br by symmetry), same k structure
    const int ar = 32 * wr + l31;
    const int br = 32 * wc + l31;
    int aoff[4], boff[4];
#pragma unroll
    for (int kk = 0; kk < 4; ++kk) {
        const int ph = ((2 * kk + lh) ^ l7) << 3;
        aoff[kk] = ar * 64 + ph;
        boff[kk] = br * 64 + ph;
    }
    // C store (transposed): plane row = br, cols 32wr + 8g + 4lh + (0..3)
    int soff[4];
    int rowg[4];
#pragma unroll
    for (int g = 0; g < 4; ++g) {
        rowg[g] = 32 * wr + 8 * g + 4 * lh;
        soff[g] = br * 64 + (((4 * wr + g) ^ l7) << 3) + 4 * lh;
    }

    const float aLo = 0.09f, aHi = 6.3f;
    const float mC = 0.5f * (aLo + aHi), rC = 0.5f * (aHi - aLo);
    const float invR2 = 2.0f / rC;    // store 2T: Clenshaw's 2x folds into the A operand

    // ---- Phase 0: load X (f32, coalesced), 2T = 2(X - mC I)/rC -> hi/lo bf16 in P0 ----
    {
        const float4* src = (const float4*)(fin + (size_t)blk * (NN * NN));
#pragma unroll
        for (int c = 0; c < 4; ++c) {
            int v4 = c * 256 + tid;
            float4 v = src[v4];
            int e0 = v4 << 2;
            int i = e0 >> 6, j = e0 & 63;     // row i, cols j..j+3
            float t0 = (v.x - ((j + 0 == i) ? mC : 0.0f)) * invR2;
            float t1 = (v.y - ((j + 1 == i) ? mC : 0.0f)) * invR2;
            float t2 = (v.z - ((j + 2 == i) ? mC : 0.0f)) * invR2;
            float t3 = (v.w - ((j + 3 == i) ? mC : 0.0f)) * invR2;
            uint2 ph, pl; split4(t0, t1, t2, t3, ph, pl);
            int idx = i * 64 + ((((j >> 3) ^ (i & 7)) << 3) | (j & 7));
            *(uint2*)(P0h + idx) = ph;
            *(uint2*)(P0l + idx) = pl;
        }
    }
    if (tid < NN) wsh[tid] = win[(size_t)blk * NN + tid];
    if (tid <= DEG) {
        // log(mC + rC t) = log(Cc) - 2 sum_k (u^k/k) T_k(t);  u<0!
        float mr = mC / rC;
        float u = -(mr - sqrtf(mr * mr - 1.0f));
        float Cc = -rC / (2.0f * u);
        if (tid == 0) cheb[0] = logf(Cc);
        else {
            float pu = powf(-u, (float)tid);          // |u|^k
            if (tid & 1) pu = -pu;                    // restore sign
            cheb[tid] = -2.0f * pu / (float)tid;
        }
    }
    __syncthreads();

    // ---- Cache 2T A-fragments in registers (A operand of every Clenshaw matmul) ----
    short8 a2h[4], a2l[4];
#pragma unroll
    for (int kk = 0; kk < 4; ++kk) {
        a2h[kk] = *(const short8*)(P0h + aoff[kk]);
        a2l[kk] = *(const short8*)(P0l + aoff[kk]);
    }

    // ---- diag mask at C-frag positions; Clenshaw init ----
    // C/D layout (m74/m101): col = lane&31, row = (reg&3) + 8*(reg>>2) + 4*(lane>>5)
    float dm[16];
    f32x16 accA, accB;
    {
        const float cD = cheb[DEG], cD1 = cheb[DEG - 1];
#pragma unroll
        for (int i = 0; i < 16; ++i) {
            int row = rowg[i >> 2] + (i & 3);
            float d = (row == br) ? 1.0f : 0.0f;
            dm[i] = d;
            float t2v = bf2f((uint16_t)P0h[swz(row, br)]);  // (2T) hi
            accB[i] = fmaf(cD, t2v, cD1 * d);   // b_{DEG-1} = c_DEG*(2T) + c_{DEG-1} I
            accA[i] = cD * d;                   // b_DEG
        }
        store16(P1h, P1l, soff, accB);
    }
    __syncthreads();

    // ---- Clenshaw pairs: accA takes k = 28,26,..,2 ; accB takes k = 27,25,..,1 ----
    for (int k = DEG - 2; k > 0; k -= 2) {
        clen_step32(accA, a2h, a2l, P1h, P1l, P0h, P0l, cheb[k],     dm, boff, soff);
        clen_step32(accB, a2h, a2l, P0h, P0l, P1h, P1l, cheb[k - 1], dm, boff, soff);
    }
    // final k=0: accA := 2*(c0 I - b_2) + (2T)*b_1 = 2L   (b_1 in P1; 0.5 folds into weights)
    {
        const float c0 = cheb[0];
#pragma unroll
        for (int i = 0; i < 16; ++i)
            accA[i] = 2.0f * fmaf(c0, dm[i], -accA[i]);
#pragma unroll
        for (int kk = 0; kk < 4; ++kk) {
            const short8 bh = *(const short8*)(P1h + boff[kk]);
            const short8 bl = *(const short8*)(P1l + boff[kk]);
            accA = MFMA32(a2h[kk], bh, accA);
            accA = MFMA32(a2h[kk], bl, accA);
            accA = MFMA32(a2l[kk], bh, accA);
        }
    }

    // ---- A = (w_i w_j / 16) L = w_i w_j * 0.03125 * (2L)  (scaling-squaring s=4) ----
    float aF[16];
    {
        const float wcol = wsh[br];
#pragma unroll
        for (int g = 0; g < 4; ++g) {
            f32x4 w4 = *(const f32x4*)(wsh + rowg[g]);   // rows rowg[g]..+3 (16B aligned)
#pragma unroll
            for (int r = 0; r < 4; ++r)
                aF[4 * g + r] = w4[r] * wcol * 0.03125f * accA[4 * g + r];
        }
    }
    // P0 free: b_2 last read at the k=1 step (barriered). X=P0 (A), Y=P1.
    store16f(P0h, P0l, soff, aF);
    __syncthreads();

    // ---- M2 = A*A -> Y ----
    f32x16 m2;
#pragma unroll
    for (int i = 0; i < 16; ++i) m2[i] = 0.0f;
    mm32(P0h, P0l, P0h, P0l, aoff, boff, m2);
    store16(P1h, P1l, soff, m2);
    __syncthreads();

    // ---- M3 = A*M2 (frags only), then G -> X, M3 -> Y ----
    float b0F[16];
    {
        f32x16 m3;
#pragma unroll
        for (int i = 0; i < 16; ++i) m3[i] = 0.0f;
        mm32(P0h, P0l, P1h, P1l, aoff, boff, m3);
        float gF[16];
#pragma unroll
        for (int i = 0; i < 16; ++i) {
            float d = dm[i];
            float a = aF[i], m2v = m2[i], m3v = m3[i];
            b0F[i] = d + a + 0.5f * m2v;
            gF[i] = (1.0f / 6.0f) * d + (1.0f / 24.0f) * a +
                    (1.0f / 120.0f) * m2v + (1.0f / 720.0f) * m3v;
        }
        __syncthreads();   // everyone done reading A(X), M2(Y)
        store16f(P0h, P0l, soff, gF);
        store16(P1h, P1l, soff, m3);
    }
    __syncthreads();

    // ---- P = b0 + G*M3 -> P0 (fixed home so squaring chain ends reading P1) ----
    {
        f32x16 pacc;
#pragma unroll
        for (int i = 0; i < 16; ++i) pacc[i] = 0.0f;
        mm32(P0h, P0l, P1h, P1l, aoff, boff, pacc);
#pragma unroll
        for (int i = 0; i < 16; ++i) pacc[i] += b0F[i];
        __syncthreads();   // everyone done reading G/M3
        store16(P0h, P0l, soff, pacc);
    }
    __syncthreads();

    // ---- 4 squarings: exp(M) = P^16. P0 -> P1 -> P0 -> P1 -> (stage) ----
    const short *Sh = P0h, *Sl = P0l;
    short *Dh = P1h, *Dl = P1l;
    for (int it = 0; it < 4; ++it) {
        f32x16 acc;
#pragma unroll
        for (int i = 0; i < 16; ++i) acc[i] = 0.0f;
        mm32(Sh, Sl, Sh, Sl, aoff, boff, acc);
        if (it < 3) {
            store16(Dh, Dl, soff, acc);
            __syncthreads();
            const short* th = Sh; const short* tl = Sl;
            Sh = Dh; Sl = Dl; Dh = (short*)th; Dl = (short*)tl;
        } else {
            // stage transposed f32 over P0 region (16 KB exactly); final mm read P1 -- no overlap.
            // same 16B-block XOR swizzle in f32 space: conflict-free write and read.
            float* stg = (float*)lds;
#pragma unroll
            for (int g = 0; g < 4; ++g) {
                f32x4 v;
#pragma unroll
                for (int r = 0; r < 4; ++r) v[r] = acc[4 * g + r];
                const int bblk = 8 * wr + 2 * g + lh;        // logical f32 16B-block of row base
                *(f32x4*)(stg + br * 64 + ((bblk ^ l7) << 2)) = v;
            }
        }
    }
    __syncthreads();

    // ---- coalesced float4 store (swizzled staging read) ----
    {
        const float* stg = (const float*)lds;
        float4* dst = (float4*)(outp + (size_t)blk * (NN * NN));
#pragma unroll
        for (int c = 0; c < 4; ++c) {
            int v4 = c * 256 + tid;
            int i = v4 >> 4, jb = v4 & 15;
            f32x4 v = *(const f32x4*)(stg + i * 64 + ((jb ^ (i & 7)) << 2));
            float4 o; o.x = v[0]; o.y = v[1]; o.z = v[2]; o.w = v[3];
            dst[v4] = o;
        }
    }
}

extern "C" void kernel_launch(void* const* d_in, const int* in_sizes, int n_in,
                              void* d_out, int out_size, void* d_ws, size_t ws_size,
                              hipStream_t stream) {
    const float* f = (const float*)d_in[0];
    const float* w = (const float*)d_in[1];
    float* o = (float*)d_out;
    int B = in_sizes[0] / (NN * NN);
    spdlogexp<<<dim3(B), dim3(256), 0, stream>>>(f, w, o);
}